// Round 1
// baseline (7571.638 us; speedup 1.0000x reference)
//
#include <hip/hip_runtime.h>

// HeteroGNN: 2 layers x 4 GATConv (single head), N=100000 nodes/type,
// E=800000 edges/type, C=128. Then mean-pool (B=256), 0.5*(pi+pj),
// linear(128->1), sigmoid. All f32.
//
// Algebraic simplification: hd = x_dst @ Wd only feeds ad = hd . a_d, so
// ad = x_dst . (Wd @ a_d)  -- a matvec with a precomputed 128-vector.
// Same trick for as = x_src . (Ws @ a_s); hs itself is still needed for
// message aggregation, so 4 GEMMs per layer (not 8).

#define NEG_SLOPE 0.2f

// ---------- helpers ----------
__device__ __forceinline__ unsigned encf(float f) {
  unsigned u = __float_as_uint(f);
  return (u & 0x80000000u) ? ~u : (u | 0x80000000u);
}
__device__ __forceinline__ float decf(unsigned u) {
  return (u & 0x80000000u) ? __uint_as_float(u & 0x7fffffffu)
                           : __uint_as_float(~u);
}

// ---------- precompute (Ws @ a_s) and (Wd @ a_d) for all 8 (layer,conv) ----------
// W: [8][128][128] row-major (f,h), att: [8][128], out: [8][128]
__global__ void precompute_wa(const float* __restrict__ W,
                              const float* __restrict__ att,
                              float* __restrict__ out) {
  int idx = blockIdx.x;   // 0..7
  int f = threadIdx.x;    // 0..127
  const float* w = W + (size_t)idx * 128 * 128 + (size_t)f * 128;
  const float* a = att + idx * 128;
  float s = 0.f;
  #pragma unroll 8
  for (int h = 0; h < 128; ++h) s += w[h] * a[h];
  out[idx * 128 + f] = s;
}

// ---------- GEMM: H[M,128] = X[M,128] @ W[128,128] ----------
// 128x128 tile per block, 256 threads, 8x8 micro-tile.
// X staged transposed in LDS (conflict-free b128 reads of 8 consecutive rows).
__global__ __launch_bounds__(256) void gemm128(const float* __restrict__ X,
                                               const float* __restrict__ W,
                                               float* __restrict__ H, int M) {
  __shared__ float Xt[128][136];   // [k][r], padded
  __shared__ float Wsm[128][128];  // [k][c]
  const int t = threadIdx.x;
  const int row0 = blockIdx.x * 128;

  // load W (16384 floats, all threads, float4)
  #pragma unroll
  for (int i = 0; i < 16; ++i) {
    int fi = (i * 256 + t) * 4;
    *(float4*)(&Wsm[0][0] + fi) = *(const float4*)(W + fi);
  }
  // load X tile rows, store transposed
  {
    int r = t >> 1;
    int cq = (t & 1) * 64;
    int gr = row0 + r;
    if (gr >= M) gr = M - 1;   // clamp (stores are guarded)
    const float4* src = (const float4*)(X + (size_t)gr * 128 + cq);
    #pragma unroll
    for (int i = 0; i < 16; ++i) {
      float4 v = src[i];
      int c = cq + i * 4;
      Xt[c + 0][r] = v.x;
      Xt[c + 1][r] = v.y;
      Xt[c + 2][r] = v.z;
      Xt[c + 3][r] = v.w;
    }
  }
  __syncthreads();

  const int c0 = (t & 15) * 8;
  const int r0 = (t >> 4) * 8;
  float acc[8][8];
  #pragma unroll
  for (int i = 0; i < 8; ++i)
    #pragma unroll
    for (int j = 0; j < 8; ++j) acc[i][j] = 0.f;

  #pragma unroll 2
  for (int k = 0; k < 128; ++k) {
    const float4 a0 = *(const float4*)&Xt[k][r0];
    const float4 a1 = *(const float4*)&Xt[k][r0 + 4];
    const float4 b0 = *(const float4*)&Wsm[k][c0];
    const float4 b1 = *(const float4*)&Wsm[k][c0 + 4];
    const float a[8] = {a0.x, a0.y, a0.z, a0.w, a1.x, a1.y, a1.z, a1.w};
    const float b[8] = {b0.x, b0.y, b0.z, b0.w, b1.x, b1.y, b1.z, b1.w};
    #pragma unroll
    for (int i = 0; i < 8; ++i)
      #pragma unroll
      for (int j = 0; j < 8; ++j) acc[i][j] = fmaf(a[i], b[j], acc[i][j]);
  }

  #pragma unroll
  for (int i = 0; i < 8; ++i) {
    int gr = row0 + r0 + i;
    if (gr < M) {
      float4 v0 = make_float4(acc[i][0], acc[i][1], acc[i][2], acc[i][3]);
      float4 v1 = make_float4(acc[i][4], acc[i][5], acc[i][6], acc[i][7]);
      *(float4*)(H + (size_t)gr * 128 + c0) = v0;
      *(float4*)(H + (size_t)gr * 128 + c0 + 4) = v1;
    }
  }
}

// ---------- attention scalars: as[n]=xsrc[n].vs, ad[n]=xdst[n].vd ----------
__global__ __launch_bounds__(256) void attn_scalars(
    const float* __restrict__ xsrc, const float* __restrict__ xdst,
    const float* __restrict__ vs, const float* __restrict__ vd,
    float* __restrict__ as_, float* __restrict__ ad_, int N) {
  int wave = (blockIdx.x * 256 + threadIdx.x) >> 6;
  int lane = threadIdx.x & 63;
  if (wave >= N) return;
  float2 xs = *(const float2*)(xsrc + (size_t)wave * 128 + lane * 2);
  float2 xd = *(const float2*)(xdst + (size_t)wave * 128 + lane * 2);
  float2 cs = *(const float2*)(vs + lane * 2);
  float2 cd = *(const float2*)(vd + lane * 2);
  float s = xs.x * cs.x + xs.y * cs.y;
  float d = xd.x * cd.x + xd.y * cd.y;
  #pragma unroll
  for (int off = 32; off >= 1; off >>= 1) {
    s += __shfl_xor(s, off);
    d += __shfl_xor(d, off);
  }
  if (lane == 0) {
    as_[wave] = s;
    ad_[wave] = d;
  }
}

// ---------- edge pass 1: e = leaky_relu(as[src]+ad[dst]); segment max ----------
__global__ void edge_max(const int* __restrict__ ei, int E,
                         const float* __restrict__ as_,
                         const float* __restrict__ ad_,
                         float* __restrict__ ebuf, unsigned* __restrict__ mbuf) {
  int e = blockIdx.x * blockDim.x + threadIdx.x;
  if (e >= E) return;
  int s = ei[e];
  int d = ei[E + e];
  float v = as_[s] + ad_[d];
  v = v > 0.f ? v : NEG_SLOPE * v;
  ebuf[e] = v;
  atomicMax(&mbuf[d], encf(v));
}

// ---------- edge pass 2: p = exp(e - m[dst]); denom[dst] += p ----------
__global__ void edge_exp(const int* __restrict__ ei, int E,
                         float* __restrict__ ebuf,
                         const unsigned* __restrict__ mbuf,
                         float* __restrict__ denom) {
  int e = blockIdx.x * blockDim.x + threadIdx.x;
  if (e >= E) return;
  int d = ei[E + e];
  float m = decf(mbuf[d]);
  float p = __expf(ebuf[e] - m);
  ebuf[e] = p;
  unsafeAtomicAdd(&denom[d], p);
}

// ---------- edge pass 3: out[dst] += (p/denom[dst]) * hs[src] ----------
// one wave per edge; lane handles 2 features (float2)
__global__ __launch_bounds__(256) void edge_scatter(
    const int* __restrict__ ei, int E, const float* __restrict__ ebuf,
    const float* __restrict__ denom, const float* __restrict__ hs,
    float* __restrict__ outbuf) {
  int wave = (blockIdx.x * 256 + threadIdx.x) >> 6;
  int lane = threadIdx.x & 63;
  if (wave >= E) return;
  int s = ei[wave];
  int d = ei[E + wave];
  float alpha = ebuf[wave] / fmaxf(denom[d], 1e-16f);
  float2 h = *(const float2*)(hs + (size_t)s * 128 + lane * 2);
  float* o = outbuf + (size_t)d * 128 + lane * 2;
  unsafeAtomicAdd(o, alpha * h.x);
  unsafeAtomicAdd(o + 1, alpha * h.y);
}

// ---------- tanh + bias (in place) ----------
__global__ void tanh_bias(float* __restrict__ x, const float* __restrict__ b1,
                          const float* __restrict__ b2, int n4) {
  int i = blockIdx.x * blockDim.x + threadIdx.x;
  if (i >= n4) return;
  float4 v = *((float4*)x + i);
  int f = (i * 4) & 127;
  float4 c1 = *(const float4*)(b1 + f);
  float4 c2 = *(const float4*)(b2 + f);
  v.x = tanhf(v.x + c1.x + c2.x);
  v.y = tanhf(v.y + c1.y + c2.y);
  v.z = tanhf(v.z + c1.z + c2.z);
  v.w = tanhf(v.w + c1.w + c2.w);
  *((float4*)x + i) = v;
}

// ---------- mean pool: pool[b] += x[n], cnt[b] += 1 ----------
__global__ __launch_bounds__(256) void pool_add(const float* __restrict__ x,
                                                const int* __restrict__ batch,
                                                float* __restrict__ pool,
                                                float* __restrict__ cnt, int N) {
  int wave = (blockIdx.x * 256 + threadIdx.x) >> 6;
  int lane = threadIdx.x & 63;
  if (wave >= N) return;
  int b = batch[wave];
  float2 v = *(const float2*)(x + (size_t)wave * 128 + lane * 2);
  float* p = pool + (size_t)b * 128 + lane * 2;
  unsafeAtomicAdd(p, v.x);
  unsafeAtomicAdd(p + 1, v.y);
  if (lane == 0) unsafeAtomicAdd(&cnt[b], 1.0f);
}

// ---------- final: out[b] = sigmoid( (0.5*(pi/ci + pj/cj)) . lin_w + lin_b ) ----------
__global__ void final_k(const float* __restrict__ pool_i,
                        const float* __restrict__ cnt_i,
                        const float* __restrict__ pool_j,
                        const float* __restrict__ cnt_j,
                        const float* __restrict__ lin_w,
                        const float* __restrict__ lin_b,
                        float* __restrict__ out) {
  int b = threadIdx.x;  // 256
  float ci = fmaxf(cnt_i[b], 1.f);
  float cj = fmaxf(cnt_j[b], 1.f);
  float acc = 0.f;
  #pragma unroll 4
  for (int f = 0; f < 128; ++f) {
    float x = 0.5f * (pool_i[(size_t)b * 128 + f] / ci +
                      pool_j[(size_t)b * 128 + f] / cj);
    acc += x * lin_w[f];
  }
  acc += lin_b[0];
  out[b] = 1.f / (1.f + __expf(-acc));
}

extern "C" void kernel_launch(void* const* d_in, const int* in_sizes, int n_in,
                              void* d_out, int out_size, void* d_ws,
                              size_t ws_size, hipStream_t stream) {
  const float* x_i = (const float*)d_in[0];
  const float* x_j = (const float*)d_in[1];
  const int* ei_arr[4] = {(const int*)d_in[2], (const int*)d_in[3],
                          (const int*)d_in[4], (const int*)d_in[5]};  // ii,jj,ij,ji
  const int* batch_i = (const int*)d_in[6];
  const int* batch_j = (const int*)d_in[7];
  const float* Ws = (const float*)d_in[8];
  const float* Wd = (const float*)d_in[9];
  const float* att_s = (const float*)d_in[10];
  const float* att_d = (const float*)d_in[11];
  const float* bias = (const float*)d_in[12];
  const float* lin_w = (const float*)d_in[13];
  const float* lin_b = (const float*)d_in[14];
  float* out = (float*)d_out;

  const int N = in_sizes[0] / 128;   // 100000
  const int E = in_sizes[2] / 2;     // 800000
  const size_t NF = (size_t)N * 128;

  // workspace carve-out (~274 MB)
  char* w = (char*)d_ws;
  auto alloc = [&](size_t bytes) {
    char* p = w;
    w += (bytes + 255) & ~(size_t)255;
    return p;
  };
  float* bufA_i = (float*)alloc(NF * 4);
  float* bufA_j = (float*)alloc(NF * 4);
  float* bufB_i = (float*)alloc(NF * 4);
  float* bufB_j = (float*)alloc(NF * 4);
  float* hs = (float*)alloc(NF * 4);
  float* asb = (float*)alloc((size_t)N * 4);
  float* adb = (float*)alloc((size_t)N * 4);
  unsigned* mbuf = (unsigned*)alloc((size_t)N * 4);
  float* denom = (float*)alloc((size_t)N * 4);
  float* ebuf = (float*)alloc((size_t)E * 4);
  float* wsas = (float*)alloc(8 * 128 * 4);
  float* wdad = (float*)alloc(8 * 128 * 4);
  float* pool = (float*)alloc(2 * 256 * 128 * 4);
  float* cnt = (float*)alloc(2 * 256 * 4);
  float* pool_i = pool;
  float* pool_j = pool + 256 * 128;
  float* cnt_i = cnt;
  float* cnt_j = cnt + 256;

  precompute_wa<<<8, 128, 0, stream>>>(Ws, att_s, wsas);
  precompute_wa<<<8, 128, 0, stream>>>(Wd, att_d, wdad);

  const int gemm_blocks = (N + 127) / 128;
  const int nodew_blocks = (N + 3) / 4;   // one wave per node
  const int edge_blocks = (E + 255) / 256;
  const int edgew_blocks = (E + 3) / 4;   // one wave per edge
  const int tanh_n4 = (int)(NF / 4);
  const int tanh_blocks = (tanh_n4 + 255) / 256;

  for (int l = 0; l < 2; ++l) {
    const float* cur_i = (l == 0) ? x_i : bufA_i;
    const float* cur_j = (l == 0) ? x_j : bufA_j;
    float* out_i = (l == 0) ? bufA_i : bufB_i;
    float* out_j = (l == 0) ? bufA_j : bufB_j;

    hipMemsetAsync(out_i, 0, NF * 4, stream);
    hipMemsetAsync(out_j, 0, NF * 4, stream);

    // conv order: c, x_src, x_dst, edges, accum target
    struct Cv { int c; const float* xs; const float* xd; const int* e; float* o; };
    Cv convs[4] = {{0, cur_i, cur_i, ei_arr[0], out_i},
                   {3, cur_j, cur_i, ei_arr[3], out_i},
                   {1, cur_j, cur_j, ei_arr[1], out_j},
                   {2, cur_i, cur_j, ei_arr[2], out_j}};

    for (int k = 0; k < 4; ++k) {
      const Cv& cv = convs[k];
      int idx = l * 4 + cv.c;
      gemm128<<<gemm_blocks, 256, 0, stream>>>(cv.xs, Ws + (size_t)idx * 16384,
                                               hs, N);
      attn_scalars<<<nodew_blocks, 256, 0, stream>>>(
          cv.xs, cv.xd, wsas + idx * 128, wdad + idx * 128, asb, adb, N);
      hipMemsetAsync(mbuf, 0, (size_t)N * 4, stream);
      hipMemsetAsync(denom, 0, (size_t)N * 4, stream);
      edge_max<<<edge_blocks, 256, 0, stream>>>(cv.e, E, asb, adb, ebuf, mbuf);
      edge_exp<<<edge_blocks, 256, 0, stream>>>(cv.e, E, ebuf, mbuf, denom);
      edge_scatter<<<edgew_blocks, 256, 0, stream>>>(cv.e, E, ebuf, denom, hs,
                                                     cv.o);
    }
    tanh_bias<<<tanh_blocks, 256, 0, stream>>>(
        out_i, bias + (size_t)(l * 4 + 0) * 128, bias + (size_t)(l * 4 + 3) * 128,
        tanh_n4);
    tanh_bias<<<tanh_blocks, 256, 0, stream>>>(
        out_j, bias + (size_t)(l * 4 + 1) * 128, bias + (size_t)(l * 4 + 2) * 128,
        tanh_n4);
  }

  hipMemsetAsync(pool, 0, 2 * 256 * 128 * 4, stream);
  hipMemsetAsync(cnt, 0, 2 * 256 * 4, stream);
  pool_add<<<nodew_blocks, 256, 0, stream>>>(bufB_i, batch_i, pool_i, cnt_i, N);
  pool_add<<<nodew_blocks, 256, 0, stream>>>(bufB_j, batch_j, pool_j, cnt_j, N);
  final_k<<<1, 256, 0, stream>>>(pool_i, cnt_i, pool_j, cnt_j, lin_w, lin_b, out);
}

// Round 2
// 2393.824 us; speedup vs baseline: 3.1630x; 3.1630x over previous
//
#include <hip/hip_runtime.h>

// HeteroGNN: 2 layers x 4 GATConv (single head), N=100000, E=800000, C=128.
// R2: CSR-gather aggregation (no feature atomics), fused conv-pair + bias +
// tanh, layer-2 aggregation fused with mean-pool. CSR built once per launch
// and reused by both layers.

#define NEG_SLOPE 0.2f

// ---------- precompute (Ws @ a_s) and (Wd @ a_d) for all 8 (layer,conv) ----------
__global__ void precompute_wa(const float* __restrict__ W,
                              const float* __restrict__ att,
                              float* __restrict__ out) {
  int idx = blockIdx.x;   // 0..7
  int f = threadIdx.x;    // 0..127
  const float* w = W + (size_t)idx * 128 * 128 + (size_t)f * 128;
  const float* a = att + idx * 128;
  float s = 0.f;
  #pragma unroll 8
  for (int h = 0; h < 128; ++h) s += w[h] * a[h];
  out[idx * 128 + f] = s;
}

// ---------- GEMM: H[M,128] = X[M,128] @ W[128,128] ----------
__global__ __launch_bounds__(256) void gemm128(const float* __restrict__ X,
                                               const float* __restrict__ W,
                                               float* __restrict__ H, int M) {
  __shared__ float Xt[128][136];   // [k][r], padded
  __shared__ float Wsm[128][128];  // [k][c]
  const int t = threadIdx.x;
  const int row0 = blockIdx.x * 128;

  #pragma unroll
  for (int i = 0; i < 16; ++i) {
    int fi = (i * 256 + t) * 4;
    *(float4*)(&Wsm[0][0] + fi) = *(const float4*)(W + fi);
  }
  {
    int r = t >> 1;
    int cq = (t & 1) * 64;
    int gr = row0 + r;
    if (gr >= M) gr = M - 1;
    const float4* src = (const float4*)(X + (size_t)gr * 128 + cq);
    #pragma unroll
    for (int i = 0; i < 16; ++i) {
      float4 v = src[i];
      int c = cq + i * 4;
      Xt[c + 0][r] = v.x;
      Xt[c + 1][r] = v.y;
      Xt[c + 2][r] = v.z;
      Xt[c + 3][r] = v.w;
    }
  }
  __syncthreads();

  const int c0 = (t & 15) * 8;
  const int r0 = (t >> 4) * 8;
  float acc[8][8];
  #pragma unroll
  for (int i = 0; i < 8; ++i)
    #pragma unroll
    for (int j = 0; j < 8; ++j) acc[i][j] = 0.f;

  #pragma unroll 2
  for (int k = 0; k < 128; ++k) {
    const float4 a0 = *(const float4*)&Xt[k][r0];
    const float4 a1 = *(const float4*)&Xt[k][r0 + 4];
    const float4 b0 = *(const float4*)&Wsm[k][c0];
    const float4 b1 = *(const float4*)&Wsm[k][c0 + 4];
    const float a[8] = {a0.x, a0.y, a0.z, a0.w, a1.x, a1.y, a1.z, a1.w};
    const float b[8] = {b0.x, b0.y, b0.z, b0.w, b1.x, b1.y, b1.z, b1.w};
    #pragma unroll
    for (int i = 0; i < 8; ++i)
      #pragma unroll
      for (int j = 0; j < 8; ++j) acc[i][j] = fmaf(a[i], b[j], acc[i][j]);
  }

  #pragma unroll
  for (int i = 0; i < 8; ++i) {
    int gr = row0 + r0 + i;
    if (gr < M) {
      float4 v0 = make_float4(acc[i][0], acc[i][1], acc[i][2], acc[i][3]);
      float4 v1 = make_float4(acc[i][4], acc[i][5], acc[i][6], acc[i][7]);
      *(float4*)(H + (size_t)gr * 128 + c0) = v0;
      *(float4*)(H + (size_t)gr * 128 + c0 + 4) = v1;
    }
  }
}

// ---------- attention scalars: as[n]=xsrc[n].vs, ad[n]=xdst[n].vd ----------
__global__ __launch_bounds__(256) void attn_scalars(
    const float* __restrict__ xsrc, const float* __restrict__ xdst,
    const float* __restrict__ vs, const float* __restrict__ vd,
    float* __restrict__ as_, float* __restrict__ ad_, int N) {
  int wave = (blockIdx.x * 256 + threadIdx.x) >> 6;
  int lane = threadIdx.x & 63;
  if (wave >= N) return;
  float2 xs = *(const float2*)(xsrc + (size_t)wave * 128 + lane * 2);
  float2 xd = *(const float2*)(xdst + (size_t)wave * 128 + lane * 2);
  float2 cs = *(const float2*)(vs + lane * 2);
  float2 cd = *(const float2*)(vd + lane * 2);
  float s = xs.x * cs.x + xs.y * cs.y;
  float d = xd.x * cd.x + xd.y * cd.y;
  #pragma unroll
  for (int off = 32; off >= 1; off >>= 1) {
    s += __shfl_xor(s, off);
    d += __shfl_xor(d, off);
  }
  if (lane == 0) {
    as_[wave] = s;
    ad_[wave] = d;
  }
}

// ---------- CSR build ----------
__global__ void hist4(const int* __restrict__ e0, const int* __restrict__ e1,
                      const int* __restrict__ e2, const int* __restrict__ e3,
                      int E, int* __restrict__ deg, int N) {
  int i = blockIdx.x * 256 + threadIdx.x;
  if (i >= E) return;
  int t = blockIdx.y;
  const int* ei = (t == 0) ? e0 : (t == 1) ? e1 : (t == 2) ? e2 : e3;
  atomicAdd(&deg[t * N + ei[E + i]], 1);
}

// 4 blocks of 1024; block t scans deg[t*N..t*N+N) -> rowptr[t*(N+1)..]
__global__ __launch_bounds__(1024) void scan4(const int* __restrict__ deg,
                                              int* __restrict__ rowptr, int N) {
  __shared__ int sums[1024];
  int t = threadIdx.x;
  int ty = blockIdx.x;
  const int* d = deg + (size_t)ty * N;
  int* rp = rowptr + (size_t)ty * (N + 1);
  int chunk = (N + 1023) / 1024;
  int lo = t * chunk;
  int hi = lo + chunk; if (hi > N) hi = N; if (lo > N) lo = N;
  int s = 0;
  for (int i = lo; i < hi; ++i) s += d[i];
  sums[t] = s;
  __syncthreads();
  for (int off = 1; off < 1024; off <<= 1) {
    int add = (t >= off) ? sums[t - off] : 0;
    __syncthreads();
    sums[t] += add;
    __syncthreads();
  }
  int run = (t == 0) ? 0 : sums[t - 1];
  for (int i = lo; i < hi; ++i) {
    rp[i] = run;
    run += d[i];
  }
  if (t == 1023) rp[N] = sums[1023];
}

__global__ void fill4(const int* __restrict__ e0, const int* __restrict__ e1,
                      const int* __restrict__ e2, const int* __restrict__ e3,
                      int E, const int* __restrict__ rowptr,
                      int* __restrict__ fill, int* __restrict__ csrc, int N) {
  int i = blockIdx.x * 256 + threadIdx.x;
  if (i >= E) return;
  int t = blockIdx.y;
  const int* ei = (t == 0) ? e0 : (t == 1) ? e1 : (t == 2) ? e2 : e3;
  int d = ei[E + i];
  int s = ei[i];
  int pos = rowptr[(size_t)t * (N + 1) + d] + atomicAdd(&fill[t * N + d], 1);
  csrc[(size_t)t * E + pos] = s;
}

// ---------- per-conv online-softmax aggregation over a dst node's edges ----------
__device__ __forceinline__ float2 agg_conv(const int* __restrict__ rowptr,
                                           const int* __restrict__ csrc,
                                           const float* __restrict__ hs,
                                           const float* __restrict__ as_,
                                           float ad, int n, int lane) {
  int beg = rowptr[n], end = rowptr[n + 1];
  float m = -INFINITY, lsum = 0.f;
  float2 acc = make_float2(0.f, 0.f);
  for (int c = beg; c < end; c += 64) {
    int k = c + lane;
    bool valid = k < end;
    int s = valid ? csrc[k] : 0;
    float e = valid ? (as_[s] + ad) : -INFINITY;
    e = e > 0.f ? e : NEG_SLOPE * e;
    float cm = e;
    #pragma unroll
    for (int off = 32; off >= 1; off >>= 1) cm = fmaxf(cm, __shfl_xor(cm, off));
    float nm = fmaxf(m, cm);
    float scale = (m == -INFINITY) ? 0.f : __expf(m - nm);
    float p = valid ? __expf(e - nm) : 0.f;
    float ps = p;
    #pragma unroll
    for (int off = 32; off >= 1; off >>= 1) ps += __shfl_xor(ps, off);
    lsum = lsum * scale + ps;
    acc.x *= scale;
    acc.y *= scale;
    int cnt = end - c; if (cnt > 64) cnt = 64;
    for (int kk = 0; kk < cnt; ++kk) {
      float pk = __shfl(p, kk);
      int sk = __shfl(s, kk);
      float2 h = *(const float2*)(hs + (size_t)sk * 128 + lane * 2);
      acc.x = fmaf(pk, h.x, acc.x);
      acc.y = fmaf(pk, h.y, acc.y);
    }
    m = nm;
  }
  float inv = 1.f / fmaxf(lsum, 1e-16f);
  acc.x *= inv;
  acc.y *= inv;
  return acc;
}

// ---------- fused: out[n] = tanh(aggA + aggB + biasA + biasB) ----------
__global__ __launch_bounds__(256) void fused_agg_store(
    const int* __restrict__ rA, const int* __restrict__ sA,
    const float* __restrict__ hA, const float* __restrict__ asA,
    const float* __restrict__ adA, const int* __restrict__ rB,
    const int* __restrict__ sB, const float* __restrict__ hB,
    const float* __restrict__ asB, const float* __restrict__ adB,
    const float* __restrict__ biasA, const float* __restrict__ biasB,
    float* __restrict__ out, int N) {
  int wave = (blockIdx.x * 256 + threadIdx.x) >> 6;
  int lane = threadIdx.x & 63;
  if (wave >= N) return;
  float2 a = agg_conv(rA, sA, hA, asA, adA[wave], wave, lane);
  float2 b = agg_conv(rB, sB, hB, asB, adB[wave], wave, lane);
  float2 b1 = *(const float2*)(biasA + lane * 2);
  float2 b2 = *(const float2*)(biasB + lane * 2);
  float2 v;
  v.x = tanhf(a.x + b.x + b1.x + b2.x);
  v.y = tanhf(a.y + b.y + b1.y + b2.y);
  *(float2*)(out + (size_t)wave * 128 + lane * 2) = v;
}

// ---------- fused layer-2: tanh(...) pooled directly (atomic) ----------
__global__ __launch_bounds__(256) void fused_agg_pool(
    const int* __restrict__ rA, const int* __restrict__ sA,
    const float* __restrict__ hA, const float* __restrict__ asA,
    const float* __restrict__ adA, const int* __restrict__ rB,
    const int* __restrict__ sB, const float* __restrict__ hB,
    const float* __restrict__ asB, const float* __restrict__ adB,
    const float* __restrict__ biasA, const float* __restrict__ biasB,
    const int* __restrict__ batch, float* __restrict__ pool, int N) {
  int wave = (blockIdx.x * 256 + threadIdx.x) >> 6;
  int lane = threadIdx.x & 63;
  if (wave >= N) return;
  float2 a = agg_conv(rA, sA, hA, asA, adA[wave], wave, lane);
  float2 b = agg_conv(rB, sB, hB, asB, adB[wave], wave, lane);
  float2 b1 = *(const float2*)(biasA + lane * 2);
  float2 b2 = *(const float2*)(biasB + lane * 2);
  float vx = tanhf(a.x + b.x + b1.x + b2.x);
  float vy = tanhf(a.y + b.y + b1.y + b2.y);
  int bb = batch[wave];
  float* p = pool + (size_t)bb * 128 + lane * 2;
  unsafeAtomicAdd(p, vx);
  unsafeAtomicAdd(p + 1, vy);
}

// ---------- batch count histogram ----------
__global__ void batch_hist(const int* __restrict__ batch,
                           float* __restrict__ cnt, int N) {
  int i = blockIdx.x * 256 + threadIdx.x;
  if (i >= N) return;
  atomicAdd(&cnt[batch[i]], 1.0f);
}

// ---------- final ----------
__global__ void final_k(const float* __restrict__ pool_i,
                        const float* __restrict__ cnt_i,
                        const float* __restrict__ pool_j,
                        const float* __restrict__ cnt_j,
                        const float* __restrict__ lin_w,
                        const float* __restrict__ lin_b,
                        float* __restrict__ out) {
  int b = threadIdx.x;  // 256
  float ci = fmaxf(cnt_i[b], 1.f);
  float cj = fmaxf(cnt_j[b], 1.f);
  float acc = 0.f;
  #pragma unroll 4
  for (int f = 0; f < 128; ++f) {
    float x = 0.5f * (pool_i[(size_t)b * 128 + f] / ci +
                      pool_j[(size_t)b * 128 + f] / cj);
    acc += x * lin_w[f];
  }
  acc += lin_b[0];
  out[b] = 1.f / (1.f + __expf(-acc));
}

extern "C" void kernel_launch(void* const* d_in, const int* in_sizes, int n_in,
                              void* d_out, int out_size, void* d_ws,
                              size_t ws_size, hipStream_t stream) {
  const float* x_i = (const float*)d_in[0];
  const float* x_j = (const float*)d_in[1];
  const int* ei_arr[4] = {(const int*)d_in[2], (const int*)d_in[3],
                          (const int*)d_in[4], (const int*)d_in[5]};  // ii,jj,ij,ji
  const int* batch_i = (const int*)d_in[6];
  const int* batch_j = (const int*)d_in[7];
  const float* Ws = (const float*)d_in[8];
  const float* att_s = (const float*)d_in[10];
  const float* att_d = (const float*)d_in[11];
  const float* bias = (const float*)d_in[12];
  const float* lin_w = (const float*)d_in[13];
  const float* lin_b = (const float*)d_in[14];
  const float* Wd = (const float*)d_in[9];
  float* out = (float*)d_out;

  const int N = in_sizes[0] / 128;   // 100000
  const int E = in_sizes[2] / 2;     // 800000
  const size_t NF = (size_t)N * 128;

  // workspace carve-out (~225 MB)
  char* w = (char*)d_ws;
  auto alloc = [&](size_t bytes) {
    char* p = w;
    w += (bytes + 255) & ~(size_t)255;
    return p;
  };
  float* bufA_i = (float*)alloc(NF * 4);
  float* bufA_j = (float*)alloc(NF * 4);
  float* hsA = (float*)alloc(NF * 4);
  float* hsB = (float*)alloc(NF * 4);
  int* csrc = (int*)alloc((size_t)4 * E * 4);
  int* rowptr = (int*)alloc((size_t)4 * (N + 1) * 4);
  int* deg = (int*)alloc((size_t)4 * N * 4);
  int* fillc = (int*)alloc((size_t)4 * N * 4);
  float* asA = (float*)alloc((size_t)N * 4);
  float* adA = (float*)alloc((size_t)N * 4);
  float* asB = (float*)alloc((size_t)N * 4);
  float* adB = (float*)alloc((size_t)N * 4);
  float* wsas = (float*)alloc(8 * 128 * 4);
  float* wdad = (float*)alloc(8 * 128 * 4);
  float* pool = (float*)alloc(2 * 256 * 128 * 4);
  float* cnt = (float*)alloc(2 * 256 * 4);
  float* pool_i = pool;
  float* pool_j = pool + 256 * 128;
  float* cnt_i = cnt;
  float* cnt_j = cnt + 256;

  // ---- CSR build (edge lists shared by both layers) ----
  hipMemsetAsync(deg, 0, (size_t)4 * N * 4, stream);
  hipMemsetAsync(fillc, 0, (size_t)4 * N * 4, stream);
  dim3 egrid((E + 255) / 256, 4);
  hist4<<<egrid, 256, 0, stream>>>(ei_arr[0], ei_arr[1], ei_arr[2], ei_arr[3],
                                   E, deg, N);
  scan4<<<4, 1024, 0, stream>>>(deg, rowptr, N);
  fill4<<<egrid, 256, 0, stream>>>(ei_arr[0], ei_arr[1], ei_arr[2], ei_arr[3],
                                   E, rowptr, fillc, csrc, N);

  precompute_wa<<<8, 128, 0, stream>>>(Ws, att_s, wsas);
  precompute_wa<<<8, 128, 0, stream>>>(Wd, att_d, wdad);

  hipMemsetAsync(pool, 0, 2 * 256 * 128 * 4, stream);
  hipMemsetAsync(cnt, 0, 2 * 256 * 4, stream);
  batch_hist<<<(N + 255) / 256, 256, 0, stream>>>(batch_i, cnt_i, N);
  batch_hist<<<(N + 255) / 256, 256, 0, stream>>>(batch_j, cnt_j, N);

  const int gemm_blocks = (N + 127) / 128;
  const int nodew_blocks = (N + 3) / 4;   // one wave per node

  // conv pair descriptors: (convA, convB) -> one output type
  // out_i: convA = c0 (ii, src=cur_i), convB = c3 (ji, src=cur_j), dst=i
  // out_j: convA = c1 (jj, src=cur_j), convB = c2 (ij, src=cur_i), dst=j
  for (int l = 0; l < 2; ++l) {
    const float* cur_i = (l == 0) ? x_i : bufA_i;
    const float* cur_j = (l == 0) ? x_j : bufA_j;

    for (int pair = 0; pair < 2; ++pair) {
      int cA = (pair == 0) ? 0 : 1;
      int cB = (pair == 0) ? 3 : 2;
      const float* srcA = (pair == 0) ? cur_i : cur_j;
      const float* srcB = (pair == 0) ? cur_j : cur_i;
      const float* dstX = (pair == 0) ? cur_i : cur_j;
      int idxA = l * 4 + cA;
      int idxB = l * 4 + cB;
      const int* rA = rowptr + (size_t)cA * (N + 1);
      const int* rB = rowptr + (size_t)cB * (N + 1);
      const int* sA = csrc + (size_t)cA * E;
      const int* sB = csrc + (size_t)cB * E;

      gemm128<<<gemm_blocks, 256, 0, stream>>>(
          srcA, Ws + (size_t)idxA * 16384, hsA, N);
      gemm128<<<gemm_blocks, 256, 0, stream>>>(
          srcB, Ws + (size_t)idxB * 16384, hsB, N);
      attn_scalars<<<nodew_blocks, 256, 0, stream>>>(
          srcA, dstX, wsas + idxA * 128, wdad + idxA * 128, asA, adA, N);
      attn_scalars<<<nodew_blocks, 256, 0, stream>>>(
          srcB, dstX, wsas + idxB * 128, wdad + idxB * 128, asB, adB, N);

      const float* bA = bias + (size_t)idxA * 128;
      const float* bB = bias + (size_t)idxB * 128;
      if (l == 0) {
        float* outb = (pair == 0) ? bufA_i : bufA_j;
        fused_agg_store<<<nodew_blocks, 256, 0, stream>>>(
            rA, sA, hsA, asA, adA, rB, sB, hsB, asB, adB, bA, bB, outb, N);
      } else {
        const int* batch = (pair == 0) ? batch_i : batch_j;
        float* poolp = (pair == 0) ? pool_i : pool_j;
        fused_agg_pool<<<nodew_blocks, 256, 0, stream>>>(
            rA, sA, hsA, asA, adA, rB, sB, hsB, asB, adB, bA, bB, batch,
            poolp, N);
      }
    }
  }

  final_k<<<1, 256, 0, stream>>>(pool_i, cnt_i, pool_j, cnt_j, lin_w, lin_b,
                                 out);
}